// Round 1
// baseline (1404.498 us; speedup 1.0000x reference)
//
#include <hip/hip_runtime.h>

// ---------------------------------------------------------------------------
// HeteroSAGE on MI355X — restructured:
//   L1:  agg_p = x_p@(Wr1_pp+Wr1_ap) + (bl1_pp+bl1_ap)
//              + scatter_pp(x_p@Wl1_pp * inv_pp) + scatter_ap(x_a@Wl1_ap * inv_ap)
//        agg_a = x_a@Wr1_pa + bl1_pa + scatter_pa(x_p@Wl1_pa * inv_pa)
//        p1 = relu(agg_p); a1 = relu(agg_a)
//   L2 pushed through W_lin (32->1):
//        out = scatter_pp(p1.v_pp * inv_pp) + scatter_ap(a1.v_ap * inv_ap)
//            + p1.v_r + c2
// ---------------------------------------------------------------------------

__global__ void prep_weights(
    const float* __restrict__ Wl1_pp, const float* __restrict__ Wr1_pp,
    const float* __restrict__ Wl1_ap, const float* __restrict__ Wr1_ap,
    const float* __restrict__ Wl1_pa, const float* __restrict__ Wr1_pa,
    const float* __restrict__ bl1_pp, const float* __restrict__ bl1_ap,
    const float* __restrict__ bl1_pa,
    const float* __restrict__ Wl2_pp, const float* __restrict__ bl2_pp,
    const float* __restrict__ Wr2_pp,
    const float* __restrict__ Wl2_ap, const float* __restrict__ bl2_ap,
    const float* __restrict__ Wr2_ap,
    const float* __restrict__ W_lin, const float* __restrict__ b_lin,
    float* __restrict__ Wcomb_p,  // 64 x 96: [Wl1_pp | Wl1_pa | Wr1_pp+Wr1_ap]
    float* __restrict__ Wcomb_a,  // 64 x 64: [Wl1_ap | Wr1_pa]
    float* __restrict__ bias_p,   // 32: bl1_pp + bl1_ap
    float* __restrict__ bias_a,   // 32: bl1_pa
    float* __restrict__ vv)       // [0:32) v_pp  [32:64) v_r  [64] c2  [96:128) v_ap
{
    int t = threadIdx.x;
    for (int idx = t; idx < 64 * 96; idx += 256) {
        int i = idx / 96, j = idx % 96;
        float v;
        if (j < 32)       v = Wl1_pp[i * 32 + j];
        else if (j < 64)  v = Wl1_pa[i * 32 + (j - 32)];
        else              v = Wr1_pp[i * 32 + (j - 64)] + Wr1_ap[i * 32 + (j - 64)];
        Wcomb_p[idx] = v;
    }
    for (int idx = t; idx < 64 * 64; idx += 256) {
        int i = idx / 64, j = idx % 64;
        Wcomb_a[idx] = (j < 32) ? Wl1_ap[i * 32 + j] : Wr1_pa[i * 32 + (j - 32)];
    }
    if (t < 32) {
        bias_p[t] = bl1_pp[t] + bl1_ap[t];
        bias_a[t] = bl1_pa[t];
        float vpp = 0.f, vr = 0.f, vap = 0.f;
        for (int j = 0; j < 32; ++j) {
            float wl = W_lin[j];
            vpp += Wl2_pp[t * 32 + j] * wl;
            vr  += (Wr2_pp[t * 32 + j] + Wr2_ap[t * 32 + j]) * wl;
            vap += Wl2_ap[t * 32 + j] * wl;
        }
        vv[t] = vpp; vv[32 + t] = vr; vv[96 + t] = vap;
    }
    if (t == 0) {
        float c = b_lin[0];
        for (int j = 0; j < 32; ++j) c += (bl2_pp[j] + bl2_ap[j]) * W_lin[j];
        vv[64] = c;
    }
}

__global__ void count_k(const int* __restrict__ dst, float* __restrict__ cnt, int E) {
    int e = blockIdx.x * blockDim.x + threadIdx.x;
    if (e < E) atomicAdd(&cnt[dst[e]], 1.0f);
}

__global__ void inv_k(float* __restrict__ c, int N) {
    int i = blockIdx.x * blockDim.x + threadIdx.x;
    if (i < N) c[i] = 1.0f / fmaxf(c[i], 1.0f);
}

// 8 nodes/block, 32 cols/node. 3 outputs per paper node.
__global__ void proj_paper(const float* __restrict__ x, const float* __restrict__ Wc,
                           const float* __restrict__ bias,
                           float* __restrict__ h_pp, float* __restrict__ h_pa,
                           float* __restrict__ agg_p, int N)
{
    __shared__ float Wlds[64 * 96];
    __shared__ float blds[32];
    for (int i = threadIdx.x; i < 64 * 96; i += 256) Wlds[i] = Wc[i];
    if (threadIdx.x < 32) blds[threadIdx.x] = bias[threadIdx.x];
    __syncthreads();
    int n = blockIdx.x * 8 + (threadIdx.x >> 5);
    int c = threadIdx.x & 31;
    if (n < N) {
        const float* xr = x + (size_t)n * 64;
        float a0 = 0.f, a1 = 0.f, a2 = 0.f;
#pragma unroll
        for (int i = 0; i < 64; ++i) {
            float xv = xr[i];
            a0 += xv * Wlds[i * 96 + c];
            a1 += xv * Wlds[i * 96 + 32 + c];
            a2 += xv * Wlds[i * 96 + 64 + c];
        }
        h_pp[(size_t)n * 32 + c] = a0;
        h_pa[(size_t)n * 32 + c] = a1;
        agg_p[(size_t)n * 32 + c] = a2 + blds[c];
    }
}

__global__ void proj_author(const float* __restrict__ x, const float* __restrict__ Wc,
                            const float* __restrict__ bias,
                            float* __restrict__ h_ap, float* __restrict__ agg_a, int N)
{
    __shared__ float Wlds[64 * 64];
    __shared__ float blds[32];
    for (int i = threadIdx.x; i < 64 * 64; i += 256) Wlds[i] = Wc[i];
    if (threadIdx.x < 32) blds[threadIdx.x] = bias[threadIdx.x];
    __syncthreads();
    int n = blockIdx.x * 8 + (threadIdx.x >> 5);
    int c = threadIdx.x & 31;
    if (n < N) {
        const float* xr = x + (size_t)n * 64;
        float a0 = 0.f, a1 = 0.f;
#pragma unroll
        for (int i = 0; i < 64; ++i) {
            float xv = xr[i];
            a0 += xv * Wlds[i * 64 + c];
            a1 += xv * Wlds[i * 64 + 32 + c];
        }
        h_ap[(size_t)n * 32 + c] = a0;
        agg_a[(size_t)n * 32 + c] = a1 + blds[c];
    }
}

// 32 lanes per edge: coalesced 128B gather + 128B atomic scatter, pre-scaled by inv[dst].
__global__ void scatter32(const float* __restrict__ h, const int* __restrict__ src,
                          const int* __restrict__ dst, const float* __restrict__ inv,
                          float* __restrict__ agg, int E)
{
    int t = blockIdx.x * blockDim.x + threadIdx.x;
    int e = t >> 5;
    if (e < E) {
        int c = t & 31;
        int s = src[e], d = dst[e];
        float v = h[(size_t)s * 32 + c] * inv[d];
        atomicAdd(&agg[(size_t)d * 32 + c], v);
    }
}

// per paper node: p1 = relu(agg_p); s_pp = p1.v_pp; out = p1.v_r + c2
__global__ void finish_p(const float* __restrict__ agg_p, const float* __restrict__ vv,
                         float* __restrict__ s_pp, float* __restrict__ out, int N)
{
    __shared__ float v0[32], v1[32];
    __shared__ float c2s;
    if (threadIdx.x < 32) { v0[threadIdx.x] = vv[threadIdx.x]; v1[threadIdx.x] = vv[32 + threadIdx.x]; }
    if (threadIdx.x == 0) c2s = vv[64];
    __syncthreads();
    int n = blockIdx.x * blockDim.x + threadIdx.x;
    if (n < N) {
        const float* r = agg_p + (size_t)n * 32;
        float d0 = 0.f, d1 = 0.f;
#pragma unroll
        for (int i = 0; i < 32; ++i) {
            float p = fmaxf(r[i], 0.f);
            d0 += p * v0[i];
            d1 += p * v1[i];
        }
        s_pp[n] = d0;
        out[n] = d1 + c2s;
    }
}

// per author node: a1 = relu(agg_a); s_ap = a1.v_ap
__global__ void finish_a(const float* __restrict__ agg_a, const float* __restrict__ vv,
                         float* __restrict__ s_ap, int N)
{
    __shared__ float v0[32];
    if (threadIdx.x < 32) v0[threadIdx.x] = vv[96 + threadIdx.x];
    __syncthreads();
    int n = blockIdx.x * blockDim.x + threadIdx.x;
    if (n < N) {
        const float* r = agg_a + (size_t)n * 32;
        float d0 = 0.f;
#pragma unroll
        for (int i = 0; i < 32; ++i) d0 += fmaxf(r[i], 0.f) * v0[i];
        s_ap[n] = d0;
    }
}

// layer-2 scalar scatter into out
__global__ void scatter1(const float* __restrict__ s, const int* __restrict__ src,
                         const int* __restrict__ dst, const float* __restrict__ inv,
                         float* __restrict__ out, int E)
{
    int e = blockIdx.x * blockDim.x + threadIdx.x;
    if (e < E) {
        int d = dst[e];
        atomicAdd(&out[d], s[src[e]] * inv[d]);
    }
}

extern "C" void kernel_launch(void* const* d_in, const int* in_sizes, int n_in,
                              void* d_out, int out_size, void* d_ws, size_t ws_size,
                              hipStream_t stream)
{
    const float* x_paper  = (const float*)d_in[0];
    const float* x_author = (const float*)d_in[1];
    const int* src_pp = (const int*)d_in[2];
    const int* dst_pp = (const int*)d_in[3];
    const int* src_ap = (const int*)d_in[4];
    const int* dst_ap = (const int*)d_in[5];
    const int* src_pa = (const int*)d_in[6];
    const int* dst_pa = (const int*)d_in[7];
    const float* Wl1_pp = (const float*)d_in[8];
    const float* bl1_pp = (const float*)d_in[9];
    const float* Wr1_pp = (const float*)d_in[10];
    const float* Wl1_ap = (const float*)d_in[11];
    const float* bl1_ap = (const float*)d_in[12];
    const float* Wr1_ap = (const float*)d_in[13];
    const float* Wl1_pa = (const float*)d_in[14];
    const float* bl1_pa = (const float*)d_in[15];
    const float* Wr1_pa = (const float*)d_in[16];
    const float* Wl2_pp = (const float*)d_in[17];
    const float* bl2_pp = (const float*)d_in[18];
    const float* Wr2_pp = (const float*)d_in[19];
    const float* Wl2_ap = (const float*)d_in[20];
    const float* bl2_ap = (const float*)d_in[21];
    const float* Wr2_ap = (const float*)d_in[22];
    const float* W_lin  = (const float*)d_in[23];
    const float* b_lin  = (const float*)d_in[24];

    const int NP = in_sizes[0] / 64;
    const int NA = in_sizes[1] / 64;
    const int E_PP = in_sizes[2];
    const int E_AP = in_sizes[4];
    const int E_PA = in_sizes[6];

    float* w = (float*)d_ws;
    float* inv_pp = w;                    // NP (counts, then inverted)
    float* inv_ap = inv_pp + NP;          // NP
    float* inv_pa = inv_ap + NP;          // NA
    float* s_pp   = inv_pa + NA;          // NP
    float* s_ap   = s_pp + NP;            // NA
    float* h_pp   = s_ap + NA;            // NP*32
    float* h_pa   = h_pp + (size_t)NP * 32;
    float* h_ap   = h_pa + (size_t)NP * 32;   // NA*32
    float* agg_p  = h_ap + (size_t)NA * 32;   // NP*32
    float* agg_a  = agg_p + (size_t)NP * 32;  // NA*32
    float* Wcomb_p = agg_a + (size_t)NA * 32; // 64*96
    float* Wcomb_a = Wcomb_p + 64 * 96;       // 64*64
    float* bias_p  = Wcomb_a + 64 * 64;       // 32
    float* bias_a  = bias_p + 32;             // 32
    float* vv      = bias_a + 32;             // 128

    float* out = (float*)d_out;

    // zero the count region
    hipMemsetAsync(w, 0, (size_t)(2 * NP + NA) * sizeof(float), stream);

    prep_weights<<<1, 256, 0, stream>>>(
        Wl1_pp, Wr1_pp, Wl1_ap, Wr1_ap, Wl1_pa, Wr1_pa,
        bl1_pp, bl1_ap, bl1_pa,
        Wl2_pp, bl2_pp, Wr2_pp, Wl2_ap, bl2_ap, Wr2_ap,
        W_lin, b_lin, Wcomb_p, Wcomb_a, bias_p, bias_a, vv);

    count_k<<<(E_PP + 255) / 256, 256, 0, stream>>>(dst_pp, inv_pp, E_PP);
    count_k<<<(E_AP + 255) / 256, 256, 0, stream>>>(dst_ap, inv_ap, E_AP);
    count_k<<<(E_PA + 255) / 256, 256, 0, stream>>>(dst_pa, inv_pa, E_PA);

    int ninv = 2 * NP + NA;
    inv_k<<<(ninv + 255) / 256, 256, 0, stream>>>(w, ninv);

    proj_paper<<<(NP + 7) / 8, 256, 0, stream>>>(x_paper, Wcomb_p, bias_p, h_pp, h_pa, agg_p, NP);
    proj_author<<<(NA + 7) / 8, 256, 0, stream>>>(x_author, Wcomb_a, bias_a, h_ap, agg_a, NA);

    scatter32<<<(int)(((size_t)E_PP * 32 + 255) / 256), 256, 0, stream>>>(h_pp, src_pp, dst_pp, inv_pp, agg_p, E_PP);
    scatter32<<<(int)(((size_t)E_AP * 32 + 255) / 256), 256, 0, stream>>>(h_ap, src_ap, dst_ap, inv_ap, agg_p, E_AP);
    scatter32<<<(int)(((size_t)E_PA * 32 + 255) / 256), 256, 0, stream>>>(h_pa, src_pa, dst_pa, inv_pa, agg_a, E_PA);

    finish_p<<<(NP + 255) / 256, 256, 0, stream>>>(agg_p, vv, s_pp, out, NP);
    finish_a<<<(NA + 255) / 256, 256, 0, stream>>>(agg_a, vv, s_ap, NA);

    scatter1<<<(E_PP + 255) / 256, 256, 0, stream>>>(s_pp, src_pp, dst_pp, inv_pp, out, E_PP);
    scatter1<<<(E_AP + 255) / 256, 256, 0, stream>>>(s_ap, src_ap, dst_ap, inv_ap, out, E_AP);
}

// Round 2
// 1181.805 us; speedup vs baseline: 1.1884x; 1.1884x over previous
//
#include <hip/hip_runtime.h>

// ---------------------------------------------------------------------------
// HeteroSAGE, pull-based:
//   build CSR per relation (hist -> chunked scan -> fill), project nodes
//   (h stored bf16, root term f32), then per-dst pull kernels fuse
//   mean + root + relu + layer-2 dot products; layer-2 is a scalar pull.
// ---------------------------------------------------------------------------

typedef unsigned short ushort_t;

__device__ inline ushort_t f2bf(float f) {
    unsigned u = __float_as_uint(f);
    unsigned r = (u + 0x7FFFu + ((u >> 16) & 1u)) >> 16;
    return (ushort_t)r;
}
__device__ inline float bf2f(ushort_t h) {
    return __uint_as_float(((unsigned)h) << 16);
}

__global__ void prep_weights(
    const float* __restrict__ Wl1_pp, const float* __restrict__ Wr1_pp,
    const float* __restrict__ Wl1_ap, const float* __restrict__ Wr1_ap,
    const float* __restrict__ Wl1_pa, const float* __restrict__ Wr1_pa,
    const float* __restrict__ bl1_pp, const float* __restrict__ bl1_ap,
    const float* __restrict__ bl1_pa,
    const float* __restrict__ Wl2_pp, const float* __restrict__ bl2_pp,
    const float* __restrict__ Wr2_pp,
    const float* __restrict__ Wl2_ap, const float* __restrict__ bl2_ap,
    const float* __restrict__ Wr2_ap,
    const float* __restrict__ W_lin, const float* __restrict__ b_lin,
    float* __restrict__ Wcomb_p,  // 64 x 96: [Wl1_pp | Wl1_pa | Wr1_pp+Wr1_ap]
    float* __restrict__ Wcomb_a,  // 64 x 64: [Wl1_ap | Wr1_pa]
    float* __restrict__ bias_p,   // 32
    float* __restrict__ bias_a,   // 32
    float* __restrict__ vv)       // [0:32) v_pp  [32:64) v_r  [64] c2  [96:128) v_ap
{
    int t = threadIdx.x;
    for (int idx = t; idx < 64 * 96; idx += 256) {
        int i = idx / 96, j = idx % 96;
        float v;
        if (j < 32)       v = Wl1_pp[i * 32 + j];
        else if (j < 64)  v = Wl1_pa[i * 32 + (j - 32)];
        else              v = Wr1_pp[i * 32 + (j - 64)] + Wr1_ap[i * 32 + (j - 64)];
        Wcomb_p[idx] = v;
    }
    for (int idx = t; idx < 64 * 64; idx += 256) {
        int i = idx / 64, j = idx % 64;
        Wcomb_a[idx] = (j < 32) ? Wl1_ap[i * 32 + j] : Wr1_pa[i * 32 + (j - 32)];
    }
    if (t < 32) {
        bias_p[t] = bl1_pp[t] + bl1_ap[t];
        bias_a[t] = bl1_pa[t];
        float vpp = 0.f, vr = 0.f, vap = 0.f;
        for (int j = 0; j < 32; ++j) {
            float wl = W_lin[j];
            vpp += Wl2_pp[t * 32 + j] * wl;
            vr  += (Wr2_pp[t * 32 + j] + Wr2_ap[t * 32 + j]) * wl;
            vap += Wl2_ap[t * 32 + j] * wl;
        }
        vv[t] = vpp; vv[32 + t] = vr; vv[96 + t] = vap;
    }
    if (t == 0) {
        float c = b_lin[0];
        for (int j = 0; j < 32; ++j) c += (bl2_pp[j] + bl2_ap[j]) * W_lin[j];
        vv[64] = c;
    }
}

__global__ void hist_k(const int* __restrict__ dst, int* __restrict__ cnt, int E) {
    int e = blockIdx.x * blockDim.x + threadIdx.x;
    if (e < E) atomicAdd(&cnt[dst[e]], 1);
}

// chunked exclusive scan: each block claims its base via atomicAdd on a total.
// Row regions are contiguous & unique; absolute placement may vary (fp-order noise only).
__global__ void scan_k(const int* __restrict__ cnt, int* __restrict__ rn,
                       int* __restrict__ total, int N)
{
    __shared__ int wsum[4];
    __shared__ int bbase;
    int base = blockIdx.x * 2048 + threadIdx.x * 8;
    int v[8]; int ts = 0;
#pragma unroll
    for (int k = 0; k < 8; ++k) {
        int idx = base + k;
        v[k] = (idx < N) ? cnt[idx] : 0;
        ts += v[k];
    }
    int lane = threadIdx.x & 63;
    int incl = ts;
#pragma unroll
    for (int off = 1; off < 64; off <<= 1) {
        int o = __shfl_up(incl, off);
        if (lane >= off) incl += o;
    }
    int wid = threadIdx.x >> 6;
    if (lane == 63) wsum[wid] = incl;
    __syncthreads();
    int btot = wsum[0] + wsum[1] + wsum[2] + wsum[3];
    if (threadIdx.x == 0) bbase = atomicAdd(total, btot);
    int woff = 0;
    for (int w = 0; w < 4; ++w) if (w < wid) woff += wsum[w];
    __syncthreads();
    int run = bbase + woff + (incl - ts);
#pragma unroll
    for (int k = 0; k < 8; ++k) {
        int idx = base + k;
        if (idx < N) rn[idx] = run;
        run += v[k];
    }
}

// rn[d] is running next-slot; after fill, rn[d] = row end (start = rn[d]-cnt[d]).
__global__ void fill_k(const int* __restrict__ src, const int* __restrict__ dst,
                       int* __restrict__ rn, int* __restrict__ csr, int E)
{
    int e = blockIdx.x * blockDim.x + threadIdx.x;
    if (e < E) {
        int pos = atomicAdd(&rn[dst[e]], 1);
        csr[pos] = src[e];
    }
}

__global__ void proj_paper(const float* __restrict__ x, const float* __restrict__ Wc,
                           const float* __restrict__ bias,
                           ushort_t* __restrict__ h_pp, ushort_t* __restrict__ h_pa,
                           float* __restrict__ root_p, int N)
{
    __shared__ float Wlds[64 * 96];
    __shared__ float blds[32];
    for (int i = threadIdx.x; i < 64 * 96; i += 256) Wlds[i] = Wc[i];
    if (threadIdx.x < 32) blds[threadIdx.x] = bias[threadIdx.x];
    __syncthreads();
    int n = blockIdx.x * 8 + (threadIdx.x >> 5);
    int c = threadIdx.x & 31;
    if (n < N) {
        const float* xr = x + (size_t)n * 64;
        float a0 = 0.f, a1 = 0.f, a2 = 0.f;
#pragma unroll
        for (int i = 0; i < 64; ++i) {
            float xv = xr[i];
            a0 += xv * Wlds[i * 96 + c];
            a1 += xv * Wlds[i * 96 + 32 + c];
            a2 += xv * Wlds[i * 96 + 64 + c];
        }
        h_pp[(size_t)n * 32 + c] = f2bf(a0);
        h_pa[(size_t)n * 32 + c] = f2bf(a1);
        root_p[(size_t)n * 32 + c] = a2 + blds[c];
    }
}

__global__ void proj_author(const float* __restrict__ x, const float* __restrict__ Wc,
                            const float* __restrict__ bias,
                            ushort_t* __restrict__ h_ap, float* __restrict__ root_a, int N)
{
    __shared__ float Wlds[64 * 64];
    __shared__ float blds[32];
    for (int i = threadIdx.x; i < 64 * 64; i += 256) Wlds[i] = Wc[i];
    if (threadIdx.x < 32) blds[threadIdx.x] = bias[threadIdx.x];
    __syncthreads();
    int n = blockIdx.x * 8 + (threadIdx.x >> 5);
    int c = threadIdx.x & 31;
    if (n < N) {
        const float* xr = x + (size_t)n * 64;
        float a0 = 0.f, a1 = 0.f;
#pragma unroll
        for (int i = 0; i < 64; ++i) {
            float xv = xr[i];
            a0 += xv * Wlds[i * 64 + c];
            a1 += xv * Wlds[i * 64 + 32 + c];
        }
        h_ap[(size_t)n * 32 + c] = f2bf(a0);
        root_a[(size_t)n * 32 + c] = a1 + blds[c];
    }
}

// 16 lanes/node; lane c owns cols {2c,2c+1} (one dword of bf16 per gather).
// Fuses: mean_pp + mean_ap + root, relu, dots with v_pp/v_r; writes s_pp & out base.
__global__ void pull_paper(const ushort_t* __restrict__ h_pp, const ushort_t* __restrict__ h_ap,
                           const float* __restrict__ root,
                           const int* __restrict__ csr_pp, const int* __restrict__ rn_pp,
                           const int* __restrict__ cnt_pp,
                           const int* __restrict__ csr_ap, const int* __restrict__ rn_ap,
                           const int* __restrict__ cnt_ap,
                           const float* __restrict__ vv,
                           float* __restrict__ s_pp, float* __restrict__ out, int N)
{
    __shared__ float v0[32], v1[32];
    __shared__ float c2s;
    if (threadIdx.x < 32) { v0[threadIdx.x] = vv[threadIdx.x]; v1[threadIdx.x] = vv[32 + threadIdx.x]; }
    if (threadIdx.x == 0) c2s = vv[64];
    __syncthreads();
    int n = blockIdx.x * 16 + (threadIdx.x >> 4);
    if (n >= N) return;
    int c = threadIdx.x & 15;
    int cpp = cnt_pp[n], epp = rn_pp[n], spp = epp - cpp;
    float a0 = 0.f, a1 = 0.f;
    for (int j = spp; j < epp; ++j) {
        int s = csr_pp[j];
        unsigned hv = *(const unsigned*)(h_pp + ((size_t)s * 32 + c * 2));
        a0 += bf2f((ushort_t)hv);
        a1 += bf2f((ushort_t)(hv >> 16));
    }
    int cap = cnt_ap[n], eap = rn_ap[n], sap = eap - cap;
    float b0 = 0.f, b1 = 0.f;
    for (int j = sap; j < eap; ++j) {
        int s = csr_ap[j];
        unsigned hv = *(const unsigned*)(h_ap + ((size_t)s * 32 + c * 2));
        b0 += bf2f((ushort_t)hv);
        b1 += bf2f((ushort_t)(hv >> 16));
    }
    float ipp = 1.0f / fmaxf((float)cpp, 1.0f);
    float iap = 1.0f / fmaxf((float)cap, 1.0f);
    float p0 = fmaxf(root[(size_t)n * 32 + 2 * c]     + a0 * ipp + b0 * iap, 0.f);
    float p1 = fmaxf(root[(size_t)n * 32 + 2 * c + 1] + a1 * ipp + b1 * iap, 0.f);
    float d0 = p0 * v0[2 * c] + p1 * v0[2 * c + 1];
    float d1 = p0 * v1[2 * c] + p1 * v1[2 * c + 1];
#pragma unroll
    for (int off = 1; off < 16; off <<= 1) {
        d0 += __shfl_xor(d0, off);
        d1 += __shfl_xor(d1, off);
    }
    if (c == 0) { s_pp[n] = d0; out[n] = d1 + c2s; }
}

__global__ void pull_author(const ushort_t* __restrict__ h_pa, const float* __restrict__ root,
                            const int* __restrict__ csr_pa, const int* __restrict__ rn_pa,
                            const int* __restrict__ cnt_pa,
                            const float* __restrict__ vv, float* __restrict__ s_ap, int N)
{
    __shared__ float v0[32];
    if (threadIdx.x < 32) v0[threadIdx.x] = vv[96 + threadIdx.x];
    __syncthreads();
    int n = blockIdx.x * 16 + (threadIdx.x >> 4);
    if (n >= N) return;
    int c = threadIdx.x & 15;
    int cp = cnt_pa[n], ep = rn_pa[n], sp = ep - cp;
    float a0 = 0.f, a1 = 0.f;
    for (int j = sp; j < ep; ++j) {
        int s = csr_pa[j];
        unsigned hv = *(const unsigned*)(h_pa + ((size_t)s * 32 + c * 2));
        a0 += bf2f((ushort_t)hv);
        a1 += bf2f((ushort_t)(hv >> 16));
    }
    float ip = 1.0f / fmaxf((float)cp, 1.0f);
    float p0 = fmaxf(root[(size_t)n * 32 + 2 * c]     + a0 * ip, 0.f);
    float p1 = fmaxf(root[(size_t)n * 32 + 2 * c + 1] + a1 * ip, 0.f);
    float d0 = p0 * v0[2 * c] + p1 * v0[2 * c + 1];
#pragma unroll
    for (int off = 1; off < 16; off <<= 1) d0 += __shfl_xor(d0, off);
    if (c == 0) s_ap[n] = d0;
}

// layer-2 scalar pull: one thread per paper node, no atomics.
__global__ void pull2(const float* __restrict__ s_pp, const float* __restrict__ s_ap,
                      const int* __restrict__ csr_pp, const int* __restrict__ rn_pp,
                      const int* __restrict__ cnt_pp,
                      const int* __restrict__ csr_ap, const int* __restrict__ rn_ap,
                      const int* __restrict__ cnt_ap,
                      float* __restrict__ out, int N)
{
    int n = blockIdx.x * blockDim.x + threadIdx.x;
    if (n >= N) return;
    int k1 = cnt_pp[n], e1 = rn_pp[n], b1 = e1 - k1;
    float t = 0.f;
    for (int j = b1; j < e1; ++j) t += s_pp[csr_pp[j]];
    int k2 = cnt_ap[n], e2 = rn_ap[n], b2 = e2 - k2;
    float u = 0.f;
    for (int j = b2; j < e2; ++j) u += s_ap[csr_ap[j]];
    out[n] += t / fmaxf((float)k1, 1.f) + u / fmaxf((float)k2, 1.f);
}

extern "C" void kernel_launch(void* const* d_in, const int* in_sizes, int n_in,
                              void* d_out, int out_size, void* d_ws, size_t ws_size,
                              hipStream_t stream)
{
    const float* x_paper  = (const float*)d_in[0];
    const float* x_author = (const float*)d_in[1];
    const int* src_pp = (const int*)d_in[2];
    const int* dst_pp = (const int*)d_in[3];
    const int* src_ap = (const int*)d_in[4];
    const int* dst_ap = (const int*)d_in[5];
    const int* src_pa = (const int*)d_in[6];
    const int* dst_pa = (const int*)d_in[7];
    const float* Wl1_pp = (const float*)d_in[8];
    const float* bl1_pp = (const float*)d_in[9];
    const float* Wr1_pp = (const float*)d_in[10];
    const float* Wl1_ap = (const float*)d_in[11];
    const float* bl1_ap = (const float*)d_in[12];
    const float* Wr1_ap = (const float*)d_in[13];
    const float* Wl1_pa = (const float*)d_in[14];
    const float* bl1_pa = (const float*)d_in[15];
    const float* Wr1_pa = (const float*)d_in[16];
    const float* Wl2_pp = (const float*)d_in[17];
    const float* bl2_pp = (const float*)d_in[18];
    const float* Wr2_pp = (const float*)d_in[19];
    const float* Wl2_ap = (const float*)d_in[20];
    const float* bl2_ap = (const float*)d_in[21];
    const float* Wr2_ap = (const float*)d_in[22];
    const float* W_lin  = (const float*)d_in[23];
    const float* b_lin  = (const float*)d_in[24];

    const int NP = in_sizes[0] / 64;
    const int NA = in_sizes[1] / 64;
    const int E_PP = in_sizes[2];
    const int E_AP = in_sizes[4];
    const int E_PA = in_sizes[6];

    // ---- workspace layout (ints, then floats, then bf16) ----
    char* wp = (char*)d_ws;
    int* cnt_pp = (int*)wp;             wp += (size_t)NP * 4;
    int* cnt_ap = (int*)wp;             wp += (size_t)NP * 4;
    int* cnt_pa = (int*)wp;             wp += (size_t)NA * 4;
    int* totals = (int*)wp;             wp += 4 * 4;           // 3 used
    int* rn_pp  = (int*)wp;             wp += (size_t)NP * 4;
    int* rn_ap  = (int*)wp;             wp += (size_t)NP * 4;
    int* rn_pa  = (int*)wp;             wp += (size_t)NA * 4;
    int* csr_pp = (int*)wp;             wp += (size_t)E_PP * 4;
    int* csr_ap = (int*)wp;             wp += (size_t)E_AP * 4;
    int* csr_pa = (int*)wp;             wp += (size_t)E_PA * 4;
    float* root_p = (float*)wp;         wp += (size_t)NP * 32 * 4;
    float* root_a = (float*)wp;         wp += (size_t)NA * 32 * 4;
    float* s_pp   = (float*)wp;         wp += (size_t)NP * 4;
    float* s_ap   = (float*)wp;         wp += (size_t)NA * 4;
    float* Wcomb_p = (float*)wp;        wp += 64 * 96 * 4;
    float* Wcomb_a = (float*)wp;        wp += 64 * 64 * 4;
    float* bias_p  = (float*)wp;        wp += 32 * 4;
    float* bias_a  = (float*)wp;        wp += 32 * 4;
    float* vv      = (float*)wp;        wp += 128 * 4;
    ushort_t* h_pp = (ushort_t*)wp;     wp += (size_t)NP * 32 * 2;
    ushort_t* h_pa = (ushort_t*)wp;     wp += (size_t)NP * 32 * 2;
    ushort_t* h_ap = (ushort_t*)wp;     wp += (size_t)NA * 32 * 2;

    float* out = (float*)d_out;

    // zero counts + totals (contiguous at ws start)
    hipMemsetAsync(d_ws, 0, ((size_t)(2 * NP + NA) + 4) * sizeof(int), stream);

    prep_weights<<<1, 256, 0, stream>>>(
        Wl1_pp, Wr1_pp, Wl1_ap, Wr1_ap, Wl1_pa, Wr1_pa,
        bl1_pp, bl1_ap, bl1_pa,
        Wl2_pp, bl2_pp, Wr2_pp, Wl2_ap, bl2_ap, Wr2_ap,
        W_lin, b_lin, Wcomb_p, Wcomb_a, bias_p, bias_a, vv);

    hist_k<<<(E_PP + 255) / 256, 256, 0, stream>>>(dst_pp, cnt_pp, E_PP);
    hist_k<<<(E_AP + 255) / 256, 256, 0, stream>>>(dst_ap, cnt_ap, E_AP);
    hist_k<<<(E_PA + 255) / 256, 256, 0, stream>>>(dst_pa, cnt_pa, E_PA);

    scan_k<<<(NP + 2047) / 2048, 256, 0, stream>>>(cnt_pp, rn_pp, totals + 0, NP);
    scan_k<<<(NP + 2047) / 2048, 256, 0, stream>>>(cnt_ap, rn_ap, totals + 1, NP);
    scan_k<<<(NA + 2047) / 2048, 256, 0, stream>>>(cnt_pa, rn_pa, totals + 2, NA);

    fill_k<<<(E_PP + 255) / 256, 256, 0, stream>>>(src_pp, dst_pp, rn_pp, csr_pp, E_PP);
    fill_k<<<(E_AP + 255) / 256, 256, 0, stream>>>(src_ap, dst_ap, rn_ap, csr_ap, E_AP);
    fill_k<<<(E_PA + 255) / 256, 256, 0, stream>>>(src_pa, dst_pa, rn_pa, csr_pa, E_PA);

    proj_paper<<<(NP + 7) / 8, 256, 0, stream>>>(x_paper, Wcomb_p, bias_p, h_pp, h_pa, root_p, NP);
    proj_author<<<(NA + 7) / 8, 256, 0, stream>>>(x_author, Wcomb_a, bias_a, h_ap, root_a, NA);

    pull_paper<<<(NP + 15) / 16, 256, 0, stream>>>(
        h_pp, h_ap, root_p, csr_pp, rn_pp, cnt_pp, csr_ap, rn_ap, cnt_ap,
        vv, s_pp, out, NP);
    pull_author<<<(NA + 15) / 16, 256, 0, stream>>>(
        h_pa, root_a, csr_pa, rn_pa, cnt_pa, vv, s_ap, NA);

    pull2<<<(NP + 255) / 256, 256, 0, stream>>>(
        s_pp, s_ap, csr_pp, rn_pp, cnt_pp, csr_ap, rn_ap, cnt_ap, out, NP);
}